// Round 12
// baseline (30.189 us; speedup 1.0000x reference)
//
#include <hip/hip_runtime.h>

#define HH 512
#define WW 512
#define NIMG 16
#define EPSF 1e-5f
#define INV81 (1.0f / 81.0f)

// lane l receives lane l-1's value; lane 0 -> 0  (wave_shr:1, bound_ctrl=1)
__device__ __forceinline__ float dpp_shr1(float x) {
    return __int_as_float(__builtin_amdgcn_update_dpp(
        0, __float_as_int(x), 0x138, 0xF, 0xF, true));
}
// lane l receives lane l+1's value; lane 63 -> 0  (wave_shl:1, bound_ctrl=1)
__device__ __forceinline__ float dpp_shl1(float x) {
    return __int_as_float(__builtin_amdgcn_update_dpp(
        0, __float_as_int(x), 0x130, 0xF, 0xF, true));
}

// Block = 16 waves (1024 thr), one (image, 32-row strip). 24-slot LDS ring
// (96 KB) of raw rows, conflict-free float4 layout (lane-stride 16B).
// vs R11: strip 16->32 rows amortizes the 8-row vertical halo (fetch
// 1.5x -> 1.25x of compulsory, 48->40 MB total) and halves barriers per
// output row. Whole 40-row fetch issued as one prologue burst (24 rows
// to LDS + 16 rows to regs = 320 B/lane in flight during cold stream).
// 256 blocks = exactly 1/CU; XCD swizzle: bid&7 -> image pair (L2-sized).
__global__ __launch_bounds__(1024, 4) void ncc_main(const float* __restrict__ Iin,
                                                    const float* __restrict__ Jin,
                                                    double* __restrict__ acc,
                                                    unsigned* __restrict__ cnt,
                                                    float* __restrict__ out) {
    __shared__ float4 ring4[24][2][128];  // 96 KB: [slot][img][A(0..63)|B(64..127)]
    __shared__ float wsum[16];

    const int tid  = threadIdx.x;
    const int lane = tid & 63;
    const int w    = tid >> 6;           // wave id 0..15
    // XCD swizzle: xcd = bid&7 (HW round-robin); each XCD gets 2 images.
    const int xcd  = blockIdx.x & 7;
    const int idx  = blockIdx.x >> 3;    // 0..31 within XCD
    const int n    = (xcd << 1) | (idx >> 4);   // image
    const int y0   = (idx & 15) << 5;           // strip base output row (32-row strips)
    const int c0   = lane << 3;          // 8 cols per lane (global addressing)

    const float* Ib = Iin + (size_t)n * (HH * WW);
    const float* Jb = Jin + (size_t)n * (HH * WW);

    auto gload = [&](int r, float4& a0, float4& a1, float4& b0, float4& b1) {
        if (r >= 0 && r < HH) {           // wave-uniform
            const float4* pI = (const float4*)(Ib + (size_t)r * WW + c0);
            const float4* pJ = (const float4*)(Jb + (size_t)r * WW + c0);
            a0 = pI[0]; a1 = pI[1]; b0 = pJ[0]; b1 = pJ[1];
        } else {
            a0 = a1 = b0 = b1 = make_float4(0.f, 0.f, 0.f, 0.f);
        }
    };
    // slot index = (row - (y0-4)) mod 24, rows span rr in [0,40)
    auto swrite = [&](int rr, const float4& a0, const float4& a1,
                              const float4& b0, const float4& b1) {
        const int sl = rr < 24 ? rr : rr - 24;
        ring4[sl][0][lane]      = a0;     // A region: byte 16*lane
        ring4[sl][0][64 + lane] = a1;     // B region: byte 1024+16*lane
        ring4[sl][1][lane]      = b0;
        ring4[sl][1][64 + lane] = b1;
    };

    // ---- Prologue burst: all 40 rows (y0-4 .. y0+35) issued up-front ----
    // rows y0-4+w (w=0..15) -> LDS; rows y0+12+w (w<8) -> LDS;
    // rows y0+20+w (w=0..15) -> regs (held across step 0).
    float4 na0, na1, nb0, nb1;            // row y0+20+w
    {
        float4 p0, p1, q0, q1, r0, r1, s0, s1;
        gload(y0 - 4 + w, p0, p1, q0, q1);
        if (w < 8) gload(y0 + 12 + w, r0, r1, s0, s1);
        gload(y0 + 20 + w, na0, na1, nb0, nb1);
        swrite(w, p0, p1, q0, q1);                    // rr = w
        if (w < 8) swrite(16 + w, r0, r1, s0, s1);    // rr = 16+w
    }
    __syncthreads();

    // horizontal 9-box over per-col vertical sums; halos via DPP (VALU pipe)
    auto hbox = [&](const float (&C)[8], float (&B)[8]) {
        float H[16];
        #pragma unroll
        for (int k = 0; k < 4; ++k) H[k] = dpp_shr1(C[4 + k]);   // lane-1 cols
        #pragma unroll
        for (int k = 0; k < 8; ++k) H[4 + k] = C[k];
        #pragma unroll
        for (int k = 0; k < 4; ++k) H[12 + k] = dpp_shl1(C[k]);  // lane+1 cols
        float s = ((H[0] + H[1]) + (H[2] + H[3])) + ((H[4] + H[5]) + (H[6] + H[7])) + H[8];
        B[0] = s;
        #pragma unroll
        for (int i = 1; i < 8; ++i) { s += H[i + 8] - H[i - 1]; B[i] = s; }
    };

    float local = 0.f;

    // One output row at relative offset ry (= R - y0): 9-row vertical window
    // sums from LDS (conflict-free b128), horizontal 9-box, cc accumulate.
    auto dorow = [&](int ry) {
        float SI[8], SJ[8], SI2[8], SJ2[8], SIJ[8];
        #pragma unroll
        for (int c = 0; c < 8; ++c) { SI[c]=0.f; SJ[c]=0.f; SI2[c]=0.f; SJ2[c]=0.f; SIJ[c]=0.f; }
        #pragma unroll
        for (int k = 0; k < 9; ++k) {
            const int rr = ry + k;                    // window row rr in ring space
            const int sl = rr < 24 ? rr : rr - 24;
            const float4 i0 = ring4[sl][0][lane];
            const float4 i1 = ring4[sl][0][64 + lane];
            const float4 j0 = ring4[sl][1][lane];
            const float4 j1 = ring4[sl][1][64 + lane];
            const float ai[8] = {i0.x, i0.y, i0.z, i0.w, i1.x, i1.y, i1.z, i1.w};
            const float bj[8] = {j0.x, j0.y, j0.z, j0.w, j1.x, j1.y, j1.z, j1.w};
            #pragma unroll
            for (int c = 0; c < 8; ++c) {
                SI[c] += ai[c];  SJ[c] += bj[c];
                SI2[c] = fmaf(ai[c], ai[c], SI2[c]);
                SJ2[c] = fmaf(bj[c], bj[c], SJ2[c]);
                SIJ[c] = fmaf(ai[c], bj[c], SIJ[c]);
            }
        }
        float BI[8], BJ[8], BI2[8], BJ2[8], BIJ[8];
        hbox(SI, BI); hbox(SJ, BJ); hbox(SI2, BI2); hbox(SJ2, BJ2); hbox(SIJ, BIJ);
        #pragma unroll
        for (int c = 0; c < 8; ++c) {
            const float tI = BI[c] * INV81;
            const float tJ = BJ[c] * INV81;
            const float cross = fmaf(-tI, BJ[c], BIJ[c]);
            const float Iv    = fmaf(-tI, BI[c], BI2[c]);
            const float Jv    = fmaf(-tJ, BJ[c], BJ2[c]);
            const float den   = fmaf(Iv, Jv, EPSF);
            local = fmaf(cross * cross, __builtin_amdgcn_rcpf(den), local);
        }
    };

    // Step 0: output rows y0+w (windows rr = w .. w+8, all resident 0..23).
    dorow(w);
    __syncthreads();                      // all step-0 reads done
    swrite(24 + w, na0, na1, nb0, nb1);   // rows y0+20..y0+35 overwrite dead rr 0..15
    __syncthreads();                      // visible
    // Step 1: output rows y0+16+w (windows rr = 16+w .. 24+w, resident 16..39).
    dorow(16 + w);

    // wave reduction, block reduction, one atomic per block; last block finalizes
    #pragma unroll
    for (int off = 32; off > 0; off >>= 1) local += __shfl_down(local, off);
    if (lane == 0) wsum[w] = local;
    __syncthreads();
    if (tid == 0) {
        float b = 0.f;
        #pragma unroll
        for (int k = 0; k < 16; ++k) b += wsum[k];
        atomicAdd(acc, (double)b);
        __threadfence();
        const unsigned old = atomicAdd(cnt, 1u);
        if (old == gridDim.x - 1) {
            const double t = atomicAdd(acc, 0.0);   // coherent read of final sum
            out[0] = 1.0f - (float)(t * (1.0 / (double)((size_t)NIMG * HH * WW)));
        }
    }
}

extern "C" void kernel_launch(void* const* d_in, const int* in_sizes, int n_in,
                              void* d_out, int out_size, void* d_ws, size_t ws_size,
                              hipStream_t stream) {
    const float* I = (const float*)d_in[0];
    const float* J = (const float*)d_in[1];
    float* out = (float*)d_out;
    double* acc = (double*)d_ws;
    unsigned* cnt = (unsigned*)((char*)d_ws + 8);

    hipMemsetAsync(d_ws, 0, 16, stream);
    // 256 blocks = 16 images x 16 strips of 32 rows; 16 waves/block
    // = exactly 1 block/CU (96 KB LDS), 4 waves/SIMD.
    ncc_main<<<256, 1024, 0, stream>>>(I, J, acc, cnt, out);
}

// Round 13
// 29.174 us; speedup vs baseline: 1.0348x; 1.0348x over previous
//
#include <hip/hip_runtime.h>

#define HH 512
#define WW 512
#define NIMG 16
#define EPSF 1e-5f
#define INV81 (1.0f / 81.0f)

// lane l receives lane l-1's value; lane 0 -> 0  (wave_shr:1, bound_ctrl=1)
__device__ __forceinline__ float dpp_shr1(float x) {
    return __int_as_float(__builtin_amdgcn_update_dpp(
        0, __float_as_int(x), 0x138, 0xF, 0xF, true));
}
// lane l receives lane l+1's value; lane 63 -> 0  (wave_shl:1, bound_ctrl=1)
__device__ __forceinline__ float dpp_shl1(float x) {
    return __int_as_float(__builtin_amdgcn_update_dpp(
        0, __float_as_int(x), 0x130, 0xF, 0xF, true));
}

// Block = 8 waves (512 thr), one (image, 16-row strip), 64KB/16-slot LDS
// ring, conflict-free float4 layout, DPP hbox, XCD swizzle (all = R11).
// R13 change: step-1 row loads (y0+12+w) moved from the prologue to AFTER
// barrier 1. __syncthreads implies s_waitcnt vmcnt(0), so prologue-issued
// prefetches serialized the whole fetch before any compute; issuing them
// post-barrier overlaps their ~latency with step-0's LDS/VALU compute
// (T14 issue-early/write-late). Ring-slot liveness unchanged.
__global__ __launch_bounds__(512, 4) void ncc_main(const float* __restrict__ Iin,
                                                   const float* __restrict__ Jin,
                                                   double* __restrict__ acc,
                                                   unsigned* __restrict__ cnt,
                                                   float* __restrict__ out) {
    __shared__ float4 ring4[16][2][128];  // 64 KB: [slot][img][A(0..63)|B(64..127)]
    __shared__ float wsum[8];

    const int tid  = threadIdx.x;
    const int lane = tid & 63;
    const int w    = tid >> 6;           // wave id 0..7
    // XCD swizzle: xcd = bid&7 (HW round-robin); each XCD gets 2 images.
    const int xcd  = blockIdx.x & 7;
    const int idx  = blockIdx.x >> 3;    // 0..63 within XCD
    const int n    = (xcd << 1) | (idx >> 5);   // image
    const int y0   = (idx & 31) << 4;           // strip base output row
    const int c0   = lane << 3;          // 8 cols per lane (global addressing)

    const float* Ib = Iin + (size_t)n * (HH * WW);
    const float* Jb = Jin + (size_t)n * (HH * WW);

    auto gload = [&](int r, float4& a0, float4& a1, float4& b0, float4& b1) {
        if (r >= 0 && r < HH) {           // wave-uniform
            const float4* pI = (const float4*)(Ib + (size_t)r * WW + c0);
            const float4* pJ = (const float4*)(Jb + (size_t)r * WW + c0);
            a0 = pI[0]; a1 = pI[1]; b0 = pJ[0]; b1 = pJ[1];
        } else {
            a0 = a1 = b0 = b1 = make_float4(0.f, 0.f, 0.f, 0.f);
        }
    };
    auto swrite = [&](int r, const float4& a0, const float4& a1,
                             const float4& b0, const float4& b1) {
        const int sl = (r + 16) & 15;
        ring4[sl][0][lane]      = a0;     // A region: byte 16*lane
        ring4[sl][0][64 + lane] = a1;     // B region: byte 1024+16*lane
        ring4[sl][1][lane]      = b0;
        ring4[sl][1][64 + lane] = b1;
    };

    // Prologue: ONLY the 16 step-0 window rows (y0-4 .. y0+11), 2 per wave.
    {
        float4 p0, p1, q0, q1, r0, r1, s0, s1;
        gload(y0 - 4 + w, p0, p1, q0, q1);
        gload(y0 + 4 + w, r0, r1, s0, s1);
        swrite(y0 - 4 + w, p0, p1, q0, q1);
        swrite(y0 + 4 + w, r0, r1, s0, s1);
    }
    __syncthreads();                      // barrier 1 (vmcnt(0): 16 rows only)

    // Step-1 rows issued NOW: latency hides under step-0 compute below.
    float4 na0, na1, nb0, nb1;            // row y0+12+w
    gload(y0 + 12 + w, na0, na1, nb0, nb1);

    // horizontal 9-box over per-col vertical sums; halos via DPP (VALU pipe)
    auto hbox = [&](const float (&C)[8], float (&B)[8]) {
        float H[16];
        #pragma unroll
        for (int k = 0; k < 4; ++k) H[k] = dpp_shr1(C[4 + k]);   // lane-1 cols
        #pragma unroll
        for (int k = 0; k < 8; ++k) H[4 + k] = C[k];
        #pragma unroll
        for (int k = 0; k < 4; ++k) H[12 + k] = dpp_shl1(C[k]);  // lane+1 cols
        float s = ((H[0] + H[1]) + (H[2] + H[3])) + ((H[4] + H[5]) + (H[6] + H[7])) + H[8];
        B[0] = s;
        #pragma unroll
        for (int i = 1; i < 8; ++i) { s += H[i + 8] - H[i - 1]; B[i] = s; }
    };

    float local = 0.f;

    // One output row R: 9-row vertical window sums from LDS (conflict-free
    // b128 reads), then horizontal 9-box + cc. Row-by-row accumulate.
    auto dorow = [&](int R) {
        float SI[8], SJ[8], SI2[8], SJ2[8], SIJ[8];
        #pragma unroll
        for (int c = 0; c < 8; ++c) { SI[c]=0.f; SJ[c]=0.f; SI2[c]=0.f; SJ2[c]=0.f; SIJ[c]=0.f; }
        #pragma unroll
        for (int k = 0; k < 9; ++k) {
            const int sl = (R - 4 + k + 16) & 15;
            const float4 i0 = ring4[sl][0][lane];
            const float4 i1 = ring4[sl][0][64 + lane];
            const float4 j0 = ring4[sl][1][lane];
            const float4 j1 = ring4[sl][1][64 + lane];
            const float ai[8] = {i0.x, i0.y, i0.z, i0.w, i1.x, i1.y, i1.z, i1.w};
            const float bj[8] = {j0.x, j0.y, j0.z, j0.w, j1.x, j1.y, j1.z, j1.w};
            #pragma unroll
            for (int c = 0; c < 8; ++c) {
                SI[c] += ai[c];  SJ[c] += bj[c];
                SI2[c] = fmaf(ai[c], ai[c], SI2[c]);
                SJ2[c] = fmaf(bj[c], bj[c], SJ2[c]);
                SIJ[c] = fmaf(ai[c], bj[c], SIJ[c]);
            }
        }
        float BI[8], BJ[8], BI2[8], BJ2[8], BIJ[8];
        hbox(SI, BI); hbox(SJ, BJ); hbox(SI2, BI2); hbox(SJ2, BJ2); hbox(SIJ, BIJ);
        #pragma unroll
        for (int c = 0; c < 8; ++c) {
            const float tI = BI[c] * INV81;
            const float tJ = BJ[c] * INV81;
            const float cross = fmaf(-tI, BJ[c], BIJ[c]);
            const float Iv    = fmaf(-tI, BI[c], BI2[c]);
            const float Jv    = fmaf(-tJ, BJ[c], BJ2[c]);
            const float den   = fmaf(Iv, Jv, EPSF);
            local = fmaf(cross * cross, __builtin_amdgcn_rcpf(den), local);
        }
    };

    // Step 0: rows y0 .. y0+7 (windows y0-4 .. y0+11, all resident).
    dorow(y0 + w);
    __syncthreads();                      // barrier 2: step-0 reads done;
                                          // implicit vmcnt(0) lands AFTER
                                          // ~6us of compute covered the loads
    swrite(y0 + 12 + w, na0, na1, nb0, nb1);  // overwrite dead slots (-4..+3)
    __syncthreads();                      // barrier 3: rows +12..+19 visible
    // Step 1: rows y0+8 .. y0+15 (windows y0+4 .. y0+19, all resident).
    dorow(y0 + 8 + w);

    // wave reduction, block reduction, one atomic per block; last block finalizes
    #pragma unroll
    for (int off = 32; off > 0; off >>= 1) local += __shfl_down(local, off);
    if (lane == 0) wsum[w] = local;
    __syncthreads();
    if (tid == 0) {
        float b = 0.f;
        #pragma unroll
        for (int k = 0; k < 8; ++k) b += wsum[k];
        atomicAdd(acc, (double)b);
        __threadfence();
        const unsigned old = atomicAdd(cnt, 1u);
        if (old == gridDim.x - 1) {
            const double t = atomicAdd(acc, 0.0);   // coherent read of final sum
            out[0] = 1.0f - (float)(t * (1.0 / (double)((size_t)NIMG * HH * WW)));
        }
    }
}

extern "C" void kernel_launch(void* const* d_in, const int* in_sizes, int n_in,
                              void* d_out, int out_size, void* d_ws, size_t ws_size,
                              hipStream_t stream) {
    const float* I = (const float*)d_in[0];
    const float* J = (const float*)d_in[1];
    float* out = (float*)d_out;
    double* acc = (double*)d_ws;
    unsigned* cnt = (unsigned*)((char*)d_ws + 8);

    hipMemsetAsync(d_ws, 0, 16, stream);
    // 512 blocks = 16 images x 32 strips of 16 rows; 8 waves/block.
    // bid&7 = XCD (HW round-robin) -> each XCD owns 2 images (4MB = L2).
    ncc_main<<<512, 512, 0, stream>>>(I, J, acc, cnt, out);
}